// Round 2
// baseline (456.535 us; speedup 1.0000x reference)
//
#include <hip/hip_runtime.h>
#include <math.h>

// EntmaxBisect: rows of d=4096, alpha=1.5 (Xs = 0.5*X), p = 1/4095 (faithful
// to source), 50-iteration f32 bisection on t in [m-1, m-1/64].
//
// Design: one 256-thread block per row. Row kept in registers (4x float4 per
// thread). Candidates (Xs > m-1 — the only elements that can ever be in
// support) compacted into LDS once (~300-500 of 4096 for Gaussian data).
// Bisection runs on wave 0 only (shuffle reduction, no barriers in loop);
// waves 1-3 sleep at __syncthreads. Early-exit when fl(t_min+diff)==t_min is
// bit-equivalent to finishing the 50 iterations (round-to-nearest monotone,
// t_min can never change afterwards, and the reference's final t also rounds
// to t_min).

static constexpr int D = 4096;
static constexpr int NT = 256;
static constexpr float P = (float)(1.0 / 4095.0);   // matches f32(1.0/(d-1))

__device__ __forceinline__ float pow_p(float u) {
    // u^P = 2^(P * log2(u)), u > 0 guaranteed by caller
#if __has_builtin(__builtin_amdgcn_exp2f) && __has_builtin(__builtin_amdgcn_logf)
    return __builtin_amdgcn_exp2f(P * __builtin_amdgcn_logf(u));
#else
    return exp2f(P * log2f(u));
#endif
}

__device__ __forceinline__ float wave_sum(float v) {
#pragma unroll
    for (int k = 32; k >= 1; k >>= 1) v += __shfl_xor(v, k, 64);
    return v;
}

__device__ __forceinline__ float wave_max(float v) {
#pragma unroll
    for (int k = 32; k >= 1; k >>= 1) v = fmaxf(v, __shfl_xor(v, k, 64));
    return v;
}

__global__ void __launch_bounds__(NT) entmax_bisect_kernel(
        const float* __restrict__ X, float* __restrict__ out) {
    __shared__ float s_vals[D];
    __shared__ float s_red[4];
    __shared__ int   s_cnt;
    __shared__ float s_t, s_rsum;

    const int tid  = threadIdx.x;
    const int lane = tid & 63;
    const int wid  = tid >> 6;
    const size_t rowbase = (size_t)blockIdx.x * D;
    const float4* Xv = (const float4*)(X + rowbase);
    float4*       Ov = (float4*)(out + rowbase);

    // ---- load row, scale by (alpha-1)=0.5 (exact), keep in registers ----
    float4 xs[4];
#pragma unroll
    for (int c = 0; c < 4; ++c) {
        float4 v = Xv[c * NT + tid];
        xs[c].x = 0.5f * v.x; xs[c].y = 0.5f * v.y;
        xs[c].z = 0.5f * v.z; xs[c].w = 0.5f * v.w;
    }

    // ---- block max (exact) ----
    float lmax = -3.4e38f;
#pragma unroll
    for (int c = 0; c < 4; ++c)
        lmax = fmaxf(lmax, fmaxf(fmaxf(xs[c].x, xs[c].y), fmaxf(xs[c].z, xs[c].w)));
    lmax = wave_max(lmax);
    if (tid == 0) s_cnt = 0;
    if (lane == 0) s_red[wid] = lmax;
    __syncthreads();
    const float m = fmaxf(fmaxf(s_red[0], s_red[1]), fmaxf(s_red[2], s_red[3]));
    const float tmin0 = m - 1.0f;

    // ---- compact candidates (Xs > m-1) into LDS: wave prefix + LDS atomic ----
    int c_local = 0;
#pragma unroll
    for (int c = 0; c < 4; ++c) {
        c_local += (xs[c].x > tmin0) + (xs[c].y > tmin0)
                 + (xs[c].z > tmin0) + (xs[c].w > tmin0);
    }
    int incl = c_local;
#pragma unroll
    for (int d = 1; d < 64; d <<= 1) {
        int o = __shfl_up(incl, d, 64);
        if (lane >= d) incl += o;
    }
    int wbase = 0;
    if (lane == 63) wbase = atomicAdd(&s_cnt, incl);  // incl@63 == wave total
    wbase = __shfl(wbase, 63, 64);
    int off = wbase + incl - c_local;
#pragma unroll
    for (int c = 0; c < 4; ++c) {
        if (xs[c].x > tmin0) s_vals[off++] = xs[c].x;
        if (xs[c].y > tmin0) s_vals[off++] = xs[c].y;
        if (xs[c].z > tmin0) s_vals[off++] = xs[c].z;
        if (xs[c].w > tmin0) s_vals[off++] = xs[c].w;
    }
    __syncthreads();

    // ---- bisection: wave 0 only, no block barriers inside ----
    if (wid == 0) {
        const int cnt = s_cnt;
        float t_min = tmin0;
        float diff  = (m - 0.015625f) - t_min;  // t_max - t_min, f32 as in ref
        float t     = t_min;
#pragma unroll 1
        for (int it = 0; it < 50; ++it) {
            diff *= 0.5f;                 // exact
            t = t_min + diff;
            if (t == t_min) break;        // all remaining iterations are no-ops
            float local = 0.0f;
            for (int i = lane; i < cnt; i += 64) {
                float u = s_vals[i] - t;
                if (u > 0.0f) local += pow_p(u);
            }
            float s = wave_sum(local);
            if (s - 1.0f >= 0.0f) t_min = t;
        }
        // final sum at the last probed t (ref: Z = zfun(t), t from last iter)
        float local = 0.0f;
        for (int i = lane; i < cnt; i += 64) {
            float u = s_vals[i] - t;
            if (u > 0.0f) local += pow_p(u);
        }
        float s = wave_sum(local);
        if (lane == 0) { s_t = t; s_rsum = 1.0f / s; }
    }
    __syncthreads();
    const float tf = s_t, rsum = s_rsum;

    // ---- epilogue: Z(tf)/sum from registers, coalesced float4 stores ----
#pragma unroll
    for (int c = 0; c < 4; ++c) {
        float4 o; float u;
        u = xs[c].x - tf; o.x = (u > 0.0f) ? pow_p(u) * rsum : 0.0f;
        u = xs[c].y - tf; o.y = (u > 0.0f) ? pow_p(u) * rsum : 0.0f;
        u = xs[c].z - tf; o.z = (u > 0.0f) ? pow_p(u) * rsum : 0.0f;
        u = xs[c].w - tf; o.w = (u > 0.0f) ? pow_p(u) * rsum : 0.0f;
        Ov[c * NT + tid] = o;
    }
}

extern "C" void kernel_launch(void* const* d_in, const int* in_sizes, int n_in,
                              void* d_out, int out_size, void* d_ws, size_t ws_size,
                              hipStream_t stream) {
    const float* X = (const float*)d_in[0];
    float* O = (float*)d_out;
    const int nrows = in_sizes[0] / D;
    hipLaunchKernelGGL(entmax_bisect_kernel, dim3(nrows), dim3(NT), 0, stream, X, O);
}

// Round 3
// 428.150 us; speedup vs baseline: 1.0663x; 1.0663x over previous
//
#include <hip/hip_runtime.h>
#include <math.h>

// EntmaxBisect, d=4096, alpha=1.5, p=1/4095 (faithful to source).
//
// Collapse: every positive term u^p with p=1/4095 lies in [0.975, 1), so
// sum(Z) >= 1  <=>  at least 2 elements above t  <=>  second_max(Xs) > t.
// The 50-iteration bisection is therefore a pure scalar binary search toward
// second_max — no per-iteration reduction needed. Early-exit when
// fl(t_min+diff)==t_min is bit-equivalent to finishing all 50 iterations
// (round-to-nearest monotone in diff; t_min can never change afterwards and
// the reference's final t also rounds to t_min).
//
// Kernel: one 256-thread block per row, row in registers (4x float4/thread).
// Phase 1: block top-2 reduction (shuffle pair-merge + 4-slot LDS).
// Phase 2: all threads redundantly run the uniform scalar bisection.
// Phase 3: block sum of Z(t_final) (pow taken by ~2 lanes only), normalize,
// coalesced float4 store.

static constexpr int D = 4096;
static constexpr int NT = 256;
static constexpr float P = (float)(1.0 / 4095.0);   // matches f32(1.0/(d-1))

__device__ __forceinline__ float pow_p(float u) {
#if __has_builtin(__builtin_amdgcn_exp2f) && __has_builtin(__builtin_amdgcn_logf)
    return __builtin_amdgcn_exp2f(P * __builtin_amdgcn_logf(u));
#else
    return exp2f(P * log2f(u));
#endif
}

__device__ __forceinline__ float wave_sum(float v) {
#pragma unroll
    for (int k = 32; k >= 1; k >>= 1) v += __shfl_xor(v, k, 64);
    return v;
}

__device__ __forceinline__ void top2_merge(float& hi, float& lo, float ohi, float olo) {
    float nhi = fmaxf(hi, ohi);
    float nlo = fmaxf(fminf(hi, ohi), fmaxf(lo, olo));
    hi = nhi; lo = nlo;
}

__global__ void __launch_bounds__(NT) entmax_bisect_kernel(
        const float* __restrict__ X, float* __restrict__ out) {
    __shared__ float s_hi[4], s_lo[4], s_sum[4];

    const int tid  = threadIdx.x;
    const int lane = tid & 63;
    const int wid  = tid >> 6;
    const size_t rowbase = (size_t)blockIdx.x * D;
    const float4* Xv = (const float4*)(X + rowbase);
    float4*       Ov = (float4*)(out + rowbase);

    // ---- load row, scale by (alpha-1)=0.5 (exact), keep in registers ----
    float4 xs[4];
#pragma unroll
    for (int c = 0; c < 4; ++c) {
        float4 v = Xv[c * NT + tid];
        xs[c].x = 0.5f * v.x; xs[c].y = 0.5f * v.y;
        xs[c].z = 0.5f * v.z; xs[c].w = 0.5f * v.w;
    }

    // ---- per-thread top-2 ----
    float hi = -3.4e38f, lo = -3.4e38f;
#pragma unroll
    for (int c = 0; c < 4; ++c) {
        const float vv[4] = {xs[c].x, xs[c].y, xs[c].z, xs[c].w};
#pragma unroll
        for (int j = 0; j < 4; ++j) {
            float v = vv[j];
            if (v > hi) { lo = hi; hi = v; }
            else        { lo = fmaxf(lo, v); }
        }
    }
    // ---- wave top-2 (butterfly pair-merge) ----
#pragma unroll
    for (int k = 32; k >= 1; k >>= 1) {
        float ohi = __shfl_xor(hi, k, 64);
        float olo = __shfl_xor(lo, k, 64);
        top2_merge(hi, lo, ohi, olo);
    }
    if (lane == 0) { s_hi[wid] = hi; s_lo[wid] = lo; }
    __syncthreads();
    // ---- block top-2 (uniform on all threads) ----
    float m = s_hi[0], s2 = s_lo[0];
#pragma unroll
    for (int w = 1; w < 4; ++w) top2_merge(m, s2, s_hi[w], s_lo[w]);

    // ---- scalar bisection, redundantly on every thread (wave-uniform) ----
    float t_min = m - 1.0f;
    float diff  = (m - 0.015625f) - t_min;   // t_max - t_min, f32 as in ref
    float t     = t_min;
#pragma unroll 1
    for (int it = 0; it < 50; ++it) {
        diff *= 0.5f;                  // exact
        t = t_min + diff;
        if (t == t_min) break;         // all remaining iterations are no-ops
        if (t < s2) t_min = t;         // == (sum(Z(t)) - 1 >= 0), see header
    }

    // ---- sum of Z at the last probed t (ref: Z = zfun(t) from last iter) ----
    float local = 0.0f;
#pragma unroll
    for (int c = 0; c < 4; ++c) {
        const float vv[4] = {xs[c].x, xs[c].y, xs[c].z, xs[c].w};
#pragma unroll
        for (int j = 0; j < 4; ++j) {
            float u = vv[j] - t;
            if (u > 0.0f) local += pow_p(u);
        }
    }
    local = wave_sum(local);
    if (lane == 0) s_sum[wid] = local;
    __syncthreads();
    const float rsum = 1.0f / (s_sum[0] + s_sum[1] + s_sum[2] + s_sum[3]);

    // ---- epilogue: Z(t)/sum from registers, coalesced float4 stores ----
#pragma unroll
    for (int c = 0; c < 4; ++c) {
        float4 o; float u;
        u = xs[c].x - t; o.x = (u > 0.0f) ? pow_p(u) * rsum : 0.0f;
        u = xs[c].y - t; o.y = (u > 0.0f) ? pow_p(u) * rsum : 0.0f;
        u = xs[c].z - t; o.z = (u > 0.0f) ? pow_p(u) * rsum : 0.0f;
        u = xs[c].w - t; o.w = (u > 0.0f) ? pow_p(u) * rsum : 0.0f;
        Ov[c * NT + tid] = o;
    }
}

extern "C" void kernel_launch(void* const* d_in, const int* in_sizes, int n_in,
                              void* d_out, int out_size, void* d_ws, size_t ws_size,
                              hipStream_t stream) {
    const float* X = (const float*)d_in[0];
    float* O = (float*)d_out;
    const int nrows = in_sizes[0] / D;
    hipLaunchKernelGGL(entmax_bisect_kernel, dim3(nrows), dim3(NT), 0, stream, X, O);
}